// Round 10
// baseline (982.036 us; speedup 1.0000x reference)
//
#include <hip/hip_runtime.h>
#include <cstddef>

#define NN 40000
#define NE 400000
#define NG 128
#define NB_SCAN 157  // ceil(40000/256)

typedef __attribute__((ext_vector_type(8))) short bf16x8;
typedef __attribute__((ext_vector_type(4))) float f32x4;

// split fp32 x ~= hi + lo, both bf16 (RNE). |x - hi - lo| ~ 2^-17 |x|
__device__ __forceinline__ void split1(float x, unsigned short& h, unsigned short& l)
{
    unsigned u = __float_as_uint(x);
    unsigned rh = u + 0x7FFFu + ((u >> 16) & 1u);
    h = (unsigned short)(rh >> 16);
    float fh = __uint_as_float(((unsigned)h) << 16);
    float r = x - fh;
    unsigned u2 = __float_as_uint(r);
    unsigned rl = u2 + 0x7FFFu + ((u2 >> 16) & 1u);
    l = (unsigned short)(rl >> 16);
}

// ---- B[K][N] fp32 -> Bt hi/lo [N][K] bf16 (tiny, once per layer) ----
__global__ void conv_bt(const float* __restrict__ B, unsigned short* __restrict__ hi,
                        unsigned short* __restrict__ lo, int K, int N)
{
    int e = blockIdx.x * 256 + threadIdx.x;
    if (e >= K * N) return;
    int n = e / K, k = e - n * K;
    unsigned short h, l;
    split1(B[(size_t)k * N + n], h, l);
    hi[e] = h; lo[e] = l;
}

// ---- A[M][K] fp32 -> hi/lo bf16 [M][K] (one pass, 4 elems/thread) ----
__global__ __launch_bounds__(256) void conv_a(const float* __restrict__ A,
                                              unsigned short* __restrict__ hi,
                                              unsigned short* __restrict__ lo,
                                              size_t total4)
{
    size_t i = ((size_t)blockIdx.x * 256 + threadIdx.x);
    if (i >= total4) return;
    float4 v = *(const float4*)&A[i * 4];
    unsigned short h[4], l[4];
    split1(v.x, h[0], l[0]);
    split1(v.y, h[1], l[1]);
    split1(v.z, h[2], l[2]);
    split1(v.w, h[3], l[3]);
    *(uint2*)&hi[i * 4] = *(const uint2*)&h[0];
    *(uint2*)&lo[i * 4] = *(const uint2*)&l[0];
}

#define LDK 40  // padded k-stride (bf16 elems): 80B rows, 16B-aligned b128 frags

// ---------- pre-split bf16 MFMA GEMM: C = A @ B, A/B already hi/lo bf16 ----------
// A [M][K] hi/lo, B [N][K] hi/lo. 128x128 tile, BK=32, 4 waves, 3-product split.
// swz=1: XCD-partition mapping (verified r9: FETCH 258->84 MB).
__global__ __launch_bounds__(256) void gemm_ps(
    const unsigned short* __restrict__ Ahg, const unsigned short* __restrict__ Alg,
    const unsigned short* __restrict__ Bh, const unsigned short* __restrict__ Bl,
    float* __restrict__ C, int M, int K, int N, int swz)
{
    __shared__ unsigned short Ah_s[128 * LDK];
    __shared__ unsigned short Al_s[128 * LDK];
    __shared__ unsigned short Bh_s[128 * LDK];
    __shared__ unsigned short Bl_s[128 * LDK];

    int bm, bn;
    if (swz) {
        int xcd = blockIdx.x & 7;
        int loc = blockIdx.x >> 3;
        int bmi = xcd * 40 + (loc >> 2);
        if (bmi >= 313) return;
        bm = bmi * 128;
        bn = (loc & 3) * 128;
    } else {
        bm = blockIdx.x * 128;
        bn = blockIdx.y * 128;
    }

    const int t    = threadIdx.x;
    const int lane = t & 63;
    const int wid  = t >> 6;
    const int wr   = wid >> 1, wc = wid & 1;
    const int sr = t >> 1;
    const int sk = (t & 1) * 16;

    const int arow = bm + sr;
    const bool aval = (arow < M);
    const unsigned short* Ahp = Ahg + (size_t)arow * K + sk;
    const unsigned short* Alp = Alg + (size_t)arow * K + sk;
    const unsigned short* Bhp = Bh + (size_t)(bn + sr) * K + sk;
    const unsigned short* Blp = Bl + (size_t)(bn + sr) * K + sk;

    f32x4 acc[4][4];
    #pragma unroll
    for (int i = 0; i < 4; ++i)
        #pragma unroll
        for (int j = 0; j < 4; ++j) acc[i][j] = (f32x4){0.f, 0.f, 0.f, 0.f};

    uint4 ahb[2], alb[2], bhb[2], blb[2];
    const int NT = K / 32;

    auto load_tile = [&](int kt) {
        const int kb = kt * 32;
        if (aval) {
            ahb[0] = *(const uint4*)(Ahp + kb); ahb[1] = *(const uint4*)(Ahp + kb + 8);
            alb[0] = *(const uint4*)(Alp + kb); alb[1] = *(const uint4*)(Alp + kb + 8);
        } else {
            ahb[0] = ahb[1] = alb[0] = alb[1] = make_uint4(0, 0, 0, 0);
        }
        bhb[0] = *(const uint4*)(Bhp + kb); bhb[1] = *(const uint4*)(Bhp + kb + 8);
        blb[0] = *(const uint4*)(Blp + kb); blb[1] = *(const uint4*)(Blp + kb + 8);
    };

    auto store_tile = [&]() {
        *(uint4*)&Ah_s[sr * LDK + sk]     = ahb[0];
        *(uint4*)&Ah_s[sr * LDK + sk + 8] = ahb[1];
        *(uint4*)&Al_s[sr * LDK + sk]     = alb[0];
        *(uint4*)&Al_s[sr * LDK + sk + 8] = alb[1];
        *(uint4*)&Bh_s[sr * LDK + sk]     = bhb[0];
        *(uint4*)&Bh_s[sr * LDK + sk + 8] = bhb[1];
        *(uint4*)&Bl_s[sr * LDK + sk]     = blb[0];
        *(uint4*)&Bl_s[sr * LDK + sk + 8] = blb[1];
    };

    auto compute = [&]() {
        const int fr = lane & 15;
        const int fk = (lane >> 4) * 8;
        bf16x8 bhf[4], blf[4];
        #pragma unroll
        for (int ni = 0; ni < 4; ++ni) {
            bhf[ni] = *(bf16x8*)&Bh_s[(wc * 64 + ni * 16 + fr) * LDK + fk];
            blf[ni] = *(bf16x8*)&Bl_s[(wc * 64 + ni * 16 + fr) * LDK + fk];
        }
        #pragma unroll
        for (int mi = 0; mi < 4; ++mi) {
            bf16x8 ah = *(bf16x8*)&Ah_s[(wr * 64 + mi * 16 + fr) * LDK + fk];
            bf16x8 al = *(bf16x8*)&Al_s[(wr * 64 + mi * 16 + fr) * LDK + fk];
            #pragma unroll
            for (int ni = 0; ni < 4; ++ni) {
                acc[mi][ni] = __builtin_amdgcn_mfma_f32_16x16x32_bf16(ah, bhf[ni], acc[mi][ni], 0, 0, 0);
                acc[mi][ni] = __builtin_amdgcn_mfma_f32_16x16x32_bf16(ah, blf[ni], acc[mi][ni], 0, 0, 0);
                acc[mi][ni] = __builtin_amdgcn_mfma_f32_16x16x32_bf16(al, bhf[ni], acc[mi][ni], 0, 0, 0);
            }
        }
    };

    load_tile(0);
    store_tile();
    __syncthreads();
    for (int kt = 0;;) {
        if (kt + 1 < NT) load_tile(kt + 1);
        compute();
        ++kt;
        if (kt == NT) break;
        __syncthreads();
        store_tile();
        __syncthreads();
    }

    const int fr = lane & 15;
    const int fq = lane >> 4;
    #pragma unroll
    for (int mi = 0; mi < 4; ++mi) {
        int r0 = bm + wr * 64 + mi * 16 + fq * 4;
        #pragma unroll
        for (int ni = 0; ni < 4; ++ni) {
            int c = bn + wc * 64 + ni * 16 + fr;
            #pragma unroll
            for (int q = 0; q < 4; ++q) {
                int r = r0 + q;
                if (r < M) C[(size_t)r * N + c] = acc[mi][ni][q];
            }
        }
    }
}

// ---------- fallback GEMM (fp32 A, in-kernel split) — round-9 measured path ----------
__global__ __launch_bounds__(256) void gemm_split(
    const float* __restrict__ A, const unsigned short* __restrict__ Bh,
    const unsigned short* __restrict__ Bl, float* __restrict__ C,
    int M, int K, int N, int swz)
{
    __shared__ unsigned short Ah_s[128 * LDK];
    __shared__ unsigned short Al_s[128 * LDK];
    __shared__ unsigned short Bh_s[128 * LDK];
    __shared__ unsigned short Bl_s[128 * LDK];

    int bm, bn;
    if (swz) {
        int xcd = blockIdx.x & 7;
        int loc = blockIdx.x >> 3;
        int bmi = xcd * 40 + (loc >> 2);
        if (bmi >= 313) return;
        bm = bmi * 128;
        bn = (loc & 3) * 128;
    } else {
        bm = blockIdx.x * 128;
        bn = blockIdx.y * 128;
    }

    const int t    = threadIdx.x;
    const int lane = t & 63;
    const int wid  = t >> 6;
    const int wr   = wid >> 1, wc = wid & 1;
    const int sr = t >> 1;
    const int sk = (t & 1) * 16;

    const int arow = bm + sr;
    const bool aval = (arow < M);
    const float* Ap = A + (size_t)arow * K + sk;
    const unsigned short* Bhp = Bh + (size_t)(bn + sr) * K + sk;
    const unsigned short* Blp = Bl + (size_t)(bn + sr) * K + sk;

    f32x4 acc[4][4];
    #pragma unroll
    for (int i = 0; i < 4; ++i)
        #pragma unroll
        for (int j = 0; j < 4; ++j) acc[i][j] = (f32x4){0.f, 0.f, 0.f, 0.f};

    float4 abuf[4];
    uint4 bhbuf[2], blbuf[2];
    const int NT = K / 32;

    auto load_tile = [&](int kt) {
        const int kb = kt * 32;
        if (aval) {
            #pragma unroll
            for (int q = 0; q < 4; ++q) abuf[q] = *(const float4*)(Ap + kb + q * 4);
        } else {
            #pragma unroll
            for (int q = 0; q < 4; ++q) abuf[q] = make_float4(0.f, 0.f, 0.f, 0.f);
        }
        bhbuf[0] = *(const uint4*)(Bhp + kb);
        bhbuf[1] = *(const uint4*)(Bhp + kb + 8);
        blbuf[0] = *(const uint4*)(Blp + kb);
        blbuf[1] = *(const uint4*)(Blp + kb + 8);
    };

    auto store_tile = [&]() {
        unsigned short h[16], l[16];
        #pragma unroll
        for (int q = 0; q < 4; ++q) {
            split1(abuf[q].x, h[q * 4 + 0], l[q * 4 + 0]);
            split1(abuf[q].y, h[q * 4 + 1], l[q * 4 + 1]);
            split1(abuf[q].z, h[q * 4 + 2], l[q * 4 + 2]);
            split1(abuf[q].w, h[q * 4 + 3], l[q * 4 + 3]);
        }
        *(uint4*)&Ah_s[sr * LDK + sk]     = *(uint4*)&h[0];
        *(uint4*)&Ah_s[sr * LDK + sk + 8] = *(uint4*)&h[8];
        *(uint4*)&Al_s[sr * LDK + sk]     = *(uint4*)&l[0];
        *(uint4*)&Al_s[sr * LDK + sk + 8] = *(uint4*)&l[8];
        *(uint4*)&Bh_s[sr * LDK + sk]     = bhbuf[0];
        *(uint4*)&Bh_s[sr * LDK + sk + 8] = bhbuf[1];
        *(uint4*)&Bl_s[sr * LDK + sk]     = blbuf[0];
        *(uint4*)&Bl_s[sr * LDK + sk + 8] = blbuf[1];
    };

    auto compute = [&]() {
        const int fr = lane & 15;
        const int fk = (lane >> 4) * 8;
        bf16x8 bhf[4], blf[4];
        #pragma unroll
        for (int ni = 0; ni < 4; ++ni) {
            bhf[ni] = *(bf16x8*)&Bh_s[(wc * 64 + ni * 16 + fr) * LDK + fk];
            blf[ni] = *(bf16x8*)&Bl_s[(wc * 64 + ni * 16 + fr) * LDK + fk];
        }
        #pragma unroll
        for (int mi = 0; mi < 4; ++mi) {
            bf16x8 ah = *(bf16x8*)&Ah_s[(wr * 64 + mi * 16 + fr) * LDK + fk];
            bf16x8 al = *(bf16x8*)&Al_s[(wr * 64 + mi * 16 + fr) * LDK + fk];
            #pragma unroll
            for (int ni = 0; ni < 4; ++ni) {
                acc[mi][ni] = __builtin_amdgcn_mfma_f32_16x16x32_bf16(ah, bhf[ni], acc[mi][ni], 0, 0, 0);
                acc[mi][ni] = __builtin_amdgcn_mfma_f32_16x16x32_bf16(ah, blf[ni], acc[mi][ni], 0, 0, 0);
                acc[mi][ni] = __builtin_amdgcn_mfma_f32_16x16x32_bf16(al, bhf[ni], acc[mi][ni], 0, 0, 0);
            }
        }
    };

    load_tile(0);
    store_tile();
    __syncthreads();
    for (int kt = 0;;) {
        if (kt + 1 < NT) load_tile(kt + 1);
        compute();
        ++kt;
        if (kt == NT) break;
        __syncthreads();
        store_tile();
        __syncthreads();
    }

    const int fr = lane & 15;
    const int fq = lane >> 4;
    #pragma unroll
    for (int mi = 0; mi < 4; ++mi) {
        int r0 = bm + wr * 64 + mi * 16 + fq * 4;
        #pragma unroll
        for (int ni = 0; ni < 4; ++ni) {
            int c = bn + wc * 64 + ni * 16 + fr;
            #pragma unroll
            for (int q = 0; q < 4; ++q) {
                int r = r0 + q;
                if (r < M) C[(size_t)r * N + c] = acc[mi][ni][q];
            }
        }
    }
}

// ---------------- CSR build: histogram -> scan -> permute ----------------
__global__ void hist_kernel(const int* __restrict__ dst, int* __restrict__ cnt)
{
    int e = blockIdx.x * 256 + threadIdx.x;
    if (e < NE) atomicAdd(&cnt[dst[e]], 1);
}

__global__ __launch_bounds__(256) void scanA_kernel(
    const int* __restrict__ cnt, int* __restrict__ row, int* __restrict__ bsum)
{
    __shared__ int s[256];
    int t = threadIdx.x;
    int i = blockIdx.x * 256 + t;
    int v = (i < NN) ? cnt[i] : 0;
    s[t] = v;
    __syncthreads();
    #pragma unroll
    for (int off = 1; off < 256; off <<= 1) {
        int x = (t >= off) ? s[t - off] : 0;
        __syncthreads();
        s[t] += x;
        __syncthreads();
    }
    if (i < NN) row[i] = s[t] - v;     // exclusive
    if (t == 255) bsum[blockIdx.x] = s[255];
}

__global__ __launch_bounds__(256) void scanB_kernel(int* __restrict__ bsum)
{
    __shared__ int s[256];
    int t = threadIdx.x;
    int v = (t < NB_SCAN) ? bsum[t] : 0;
    s[t] = v;
    __syncthreads();
    #pragma unroll
    for (int off = 1; off < 256; off <<= 1) {
        int x = (t >= off) ? s[t - off] : 0;
        __syncthreads();
        s[t] += x;
        __syncthreads();
    }
    if (t < NB_SCAN) bsum[t] = s[t] - v;  // exclusive
}

__global__ void scanC_kernel(int* __restrict__ row, const int* __restrict__ bsum,
                             int* __restrict__ fill)
{
    int i = blockIdx.x * 256 + threadIdx.x;
    if (i < NN) {
        int r = row[i] + bsum[blockIdx.x];
        row[i] = r;
        fill[i] = r;
    }
    if (i == 0) row[NN] = NE;
}

__global__ void permute_kernel(const int* __restrict__ dst, int* __restrict__ fill,
                               int* __restrict__ eidx)
{
    int e = blockIdx.x * 256 + threadIdx.x;
    if (e < NE) {
        int pos = atomicAdd(&fill[dst[e]], 1);
        eidx[pos] = e;
    }
}

// ------------- el/er: per (node, head) dot(feat[n,h,:], a[h,:]) -------------
template <int H>
__global__ __launch_bounds__(256) void eler_kernel(
    const float* __restrict__ feat, const float* __restrict__ al,
    const float* __restrict__ ar, float* __restrict__ el, float* __restrict__ er)
{
    int wid  = (blockIdx.x * 256 + threadIdx.x) >> 6;
    int lane = threadIdx.x & 63;
    if (wid >= NN * H) return;
    int n = wid / H, h = wid % H;
    const float* f = feat + (size_t)n * (H * 128) + h * 128;
    float2 fv = *(const float2*)&f[lane * 2];
    float2 a1 = *(const float2*)&al[h * 128 + lane * 2];
    float2 a2 = *(const float2*)&ar[h * 128 + lane * 2];
    float sl = fv.x * a1.x + fv.y * a1.y;
    float sr = fv.x * a2.x + fv.y * a2.y;
    #pragma unroll
    for (int off = 32; off > 0; off >>= 1) {
        sl += __shfl_down(sl, off);
        sr += __shfl_down(sr, off);
    }
    if (lane == 0) { el[wid] = sl; er[wid] = sr; }
}

// -------- per-edge attention weight w = exp(leakyrelu(el[s]+er[d])) --------
template <int H>
__global__ __launch_bounds__(256) void edge_w_kernel(
    const int* __restrict__ src, const int* __restrict__ dst,
    const float* __restrict__ el, const float* __restrict__ er,
    float* __restrict__ w)
{
    int e = blockIdx.x * 256 + threadIdx.x;
    if (e >= NE) return;
    int s = src[e], d = dst[e];
    if constexpr (H == 4) {
        float4 a = *(const float4*)&el[s * 4];
        float4 b = *(const float4*)&er[d * 4];
        float4 v = make_float4(a.x + b.x, a.y + b.y, a.z + b.z, a.w + b.w);
        v.x = v.x > 0.f ? v.x : 0.2f * v.x;
        v.y = v.y > 0.f ? v.y : 0.2f * v.y;
        v.z = v.z > 0.f ? v.z : 0.2f * v.z;
        v.w = v.w > 0.f ? v.w : 0.2f * v.w;
        *(float4*)&w[e * 4] = make_float4(__expf(v.x), __expf(v.y), __expf(v.z), __expf(v.w));
    } else {
        float v = el[s] + er[d];
        v = v > 0.f ? v : 0.2f * v;
        w[e] = __expf(v);
    }
}

// ---- CSR gather-aggregate (one wave/dst, cooperative metadata + shfl broadcast).
// H==4: writes the layer-2 GEMM A-operand directly as bf16 hi/lo (oh/ol).
// H==1: writes fp32 out.
template <int H>
__global__ __launch_bounds__(256) void agg_kernel(
    const int* __restrict__ row, const int* __restrict__ eidx,
    const int* __restrict__ src, const float* __restrict__ w,
    const float* __restrict__ feat, const float* __restrict__ bias,
    float* __restrict__ out, unsigned short* __restrict__ oh,
    unsigned short* __restrict__ ol)
{
    int wave = (blockIdx.x * 256 + threadIdx.x) >> 6;
    int lane = threadIdx.x & 63;
    if (wave >= NN) return;
    int r0 = row[wave], r1 = row[wave + 1];
    int nedge = r1 - r0;

    if constexpr (H == 4) {
        float d0 = 0.f, d1 = 0.f, d2 = 0.f, d3 = 0.f;
        float4 a0 = {0.f,0.f,0.f,0.f}, a1 = {0.f,0.f,0.f,0.f};
        for (int base = 0; base < nedge; base += 64) {
            int cnt = nedge - base; if (cnt > 64) cnt = 64;
            int s = 0;
            float4 wv = {0.f,0.f,0.f,0.f};
            if (lane < cnt) {
                int e = eidx[r0 + base + lane];
                s = src[e];
                wv = *(const float4*)&w[e * 4];
            }
            d0 += wv.x; d1 += wv.y; d2 += wv.z; d3 += wv.w;
            int j = 0;
            for (; j + 1 < cnt; j += 2) {
                int s0 = __shfl(s, j), s1 = __shfl(s, j + 1);
                float wx0 = __shfl(wv.x, j), wy0 = __shfl(wv.y, j);
                float wz0 = __shfl(wv.z, j), ww0 = __shfl(wv.w, j);
                float wx1 = __shfl(wv.x, j + 1), wy1 = __shfl(wv.y, j + 1);
                float wz1 = __shfl(wv.z, j + 1), ww1 = __shfl(wv.w, j + 1);
                const float* f0 = feat + (size_t)s0 * 512;
                const float* f1 = feat + (size_t)s1 * 512;
                float4 p00 = *(const float4*)&f0[lane * 4];
                float4 p01 = *(const float4*)&f0[256 + lane * 4];
                float4 p10 = *(const float4*)&f1[lane * 4];
                float4 p11 = *(const float4*)&f1[256 + lane * 4];
                float alo0 = (lane & 32) ? wy0 : wx0, ahi0 = (lane & 32) ? ww0 : wz0;
                float alo1 = (lane & 32) ? wy1 : wx1, ahi1 = (lane & 32) ? ww1 : wz1;
                a0.x = fmaf(p00.x, alo0, a0.x); a0.y = fmaf(p00.y, alo0, a0.y);
                a0.z = fmaf(p00.z, alo0, a0.z); a0.w = fmaf(p00.w, alo0, a0.w);
                a1.x = fmaf(p01.x, ahi0, a1.x); a1.y = fmaf(p01.y, ahi0, a1.y);
                a1.z = fmaf(p01.z, ahi0, a1.z); a1.w = fmaf(p01.w, ahi0, a1.w);
                a0.x = fmaf(p10.x, alo1, a0.x); a0.y = fmaf(p10.y, alo1, a0.y);
                a0.z = fmaf(p10.z, alo1, a0.z); a0.w = fmaf(p10.w, alo1, a0.w);
                a1.x = fmaf(p11.x, ahi1, a1.x); a1.y = fmaf(p11.y, ahi1, a1.y);
                a1.z = fmaf(p11.z, ahi1, a1.z); a1.w = fmaf(p11.w, ahi1, a1.w);
            }
            if (j < cnt) {
                int s0 = __shfl(s, j);
                float wx0 = __shfl(wv.x, j), wy0 = __shfl(wv.y, j);
                float wz0 = __shfl(wv.z, j), ww0 = __shfl(wv.w, j);
                const float* f0 = feat + (size_t)s0 * 512;
                float4 p00 = *(const float4*)&f0[lane * 4];
                float4 p01 = *(const float4*)&f0[256 + lane * 4];
                float alo0 = (lane & 32) ? wy0 : wx0, ahi0 = (lane & 32) ? ww0 : wz0;
                a0.x = fmaf(p00.x, alo0, a0.x); a0.y = fmaf(p00.y, alo0, a0.y);
                a0.z = fmaf(p00.z, alo0, a0.z); a0.w = fmaf(p00.w, alo0, a0.w);
                a1.x = fmaf(p01.x, ahi0, a1.x); a1.y = fmaf(p01.y, ahi0, a1.y);
                a1.z = fmaf(p01.z, ahi0, a1.z); a1.w = fmaf(p01.w, ahi0, a1.w);
            }
        }
        #pragma unroll
        for (int off = 32; off > 0; off >>= 1) {
            d0 += __shfl_xor(d0, off);
            d1 += __shfl_xor(d1, off);
            d2 += __shfl_xor(d2, off);
            d3 += __shfl_xor(d3, off);
        }
        float ilo = (lane & 32) ? d1 : d0;
        float ihi = (lane & 32) ? d3 : d2;
        ilo = (nedge > 0) ? 1.0f / ilo : 0.0f;
        ihi = (nedge > 0) ? 1.0f / ihi : 0.0f;
        float4 b0 = *(const float4*)&bias[lane * 4];
        float4 b1v = *(const float4*)&bias[256 + lane * 4];
        float res[8];
        res[0] = fmaf(a0.x, ilo, b0.x);  res[1] = fmaf(a0.y, ilo, b0.y);
        res[2] = fmaf(a0.z, ilo, b0.z);  res[3] = fmaf(a0.w, ilo, b0.w);
        res[4] = fmaf(a1.x, ihi, b1v.x); res[5] = fmaf(a1.y, ihi, b1v.y);
        res[6] = fmaf(a1.z, ihi, b1v.z); res[7] = fmaf(a1.w, ihi, b1v.w);
        unsigned short hh[8], ll[8];
        #pragma unroll
        for (int q = 0; q < 8; ++q) split1(res[q], hh[q], ll[q]);
        size_t o0 = (size_t)wave * 512 + lane * 4;
        size_t o1 = (size_t)wave * 512 + 256 + lane * 4;
        *(uint2*)&oh[o0] = *(const uint2*)&hh[0];
        *(uint2*)&oh[o1] = *(const uint2*)&hh[4];
        *(uint2*)&ol[o0] = *(const uint2*)&ll[0];
        *(uint2*)&ol[o1] = *(const uint2*)&ll[4];
    } else {
        float den = 0.f;
        float2 a = {0.f, 0.f};
        for (int base = 0; base < nedge; base += 64) {
            int cnt = nedge - base; if (cnt > 64) cnt = 64;
            int s = 0;
            float wv = 0.f;
            if (lane < cnt) {
                int e = eidx[r0 + base + lane];
                s = src[e];
                wv = w[e];
            }
            den += wv;
            int j = 0;
            for (; j + 1 < cnt; j += 2) {
                int s0 = __shfl(s, j), s1 = __shfl(s, j + 1);
                float w0 = __shfl(wv, j), w1 = __shfl(wv, j + 1);
                float2 p0 = *(const float2*)&feat[(size_t)s0 * 128 + lane * 2];
                float2 p1 = *(const float2*)&feat[(size_t)s1 * 128 + lane * 2];
                a.x = fmaf(p0.x, w0, a.x); a.y = fmaf(p0.y, w0, a.y);
                a.x = fmaf(p1.x, w1, a.x); a.y = fmaf(p1.y, w1, a.y);
            }
            if (j < cnt) {
                int s0 = __shfl(s, j);
                float w0 = __shfl(wv, j);
                float2 p0 = *(const float2*)&feat[(size_t)s0 * 128 + lane * 2];
                a.x = fmaf(p0.x, w0, a.x); a.y = fmaf(p0.y, w0, a.y);
            }
        }
        #pragma unroll
        for (int off = 32; off > 0; off >>= 1) den += __shfl_xor(den, off);
        float inv = (nedge > 0) ? 1.0f / den : 0.0f;
        float2 b = *(const float2*)&bias[lane * 2];
        float* o = out + (size_t)wave * 128;
        *(float2*)&o[lane * 2] = make_float2(fmaf(a.x, inv, b.x), fmaf(a.y, inv, b.y));
    }
}

// --------- per-graph mean via binary search on sorted graph_ids ---------
__global__ __launch_bounds__(128) void graph_mean_kernel(
    const int* __restrict__ gid, const float* __restrict__ h2, float* __restrict__ hg)
{
    int g = blockIdx.x;
    int t = threadIdx.x;
    int lo = 0, hi = NN;
    while (lo < hi) { int m = (lo + hi) >> 1; if (gid[m] < g) lo = m + 1; else hi = m; }
    int start = lo;
    lo = start; hi = NN;
    while (lo < hi) { int m = (lo + hi) >> 1; if (gid[m] < g + 1) lo = m + 1; else hi = m; }
    int end = lo;
    float acc = 0.f;
    for (int n = start; n < end; ++n) acc += h2[(size_t)n * 128 + t];
    float c = fmaxf((float)(end - start), 1.0f);
    hg[g * 128 + t] = acc / c;
}

// --------- node MLP: out = relu(h @ W1 + b1) @ W2 + b2 (one node/block) ---------
__global__ __launch_bounds__(128) void node_mlp_kernel(
    const float* __restrict__ h, const float* __restrict__ W1,
    const float* __restrict__ b1, const float* __restrict__ W2,
    const float* __restrict__ b2, float* __restrict__ out)
{
    __shared__ float row[128];
    __shared__ float hid[128];
    int n = blockIdx.x;
    int t = threadIdx.x;
    row[t] = h[(size_t)n * 128 + t];
    __syncthreads();
    float acc = b1[t];
    #pragma unroll 8
    for (int k = 0; k < 128; ++k) acc = fmaf(row[k], W1[k * 128 + t], acc);
    hid[t] = fmaxf(acc, 0.f);
    __syncthreads();
    if (t < 2) {
        float o = b2[t];
        for (int k = 0; k < 128; ++k) o = fmaf(hid[k], W2[k * 2 + t], o);
        out[(size_t)n * 2 + t] = o;
    }
}

__global__ __launch_bounds__(128) void graph_mlp_kernel(
    const float* __restrict__ hg,
    const float* __restrict__ W1, const float* __restrict__ b1,
    const float* __restrict__ W2, const float* __restrict__ b2,
    float* __restrict__ out)
{
    __shared__ float row[128];
    __shared__ float hid[128];
    int g = blockIdx.x;
    int t = threadIdx.x;
    row[t] = hg[(size_t)g * 128 + t];
    __syncthreads();
    float acc = b1[t];
    #pragma unroll 8
    for (int k = 0; k < 128; ++k) acc = fmaf(row[k], W1[k * 128 + t], acc);
    hid[t] = fmaxf(acc, 0.f);
    __syncthreads();
    if (t < 2) {
        float o = b2[t];
        for (int k = 0; k < 128; ++k) o = fmaf(hid[k], W2[k * 2 + t], o);
        out[(size_t)g * 2 + t] = o;
    }
}

// ---------------------------------------------------------------------------
// workspace layout (float offsets)
static constexpr size_t O_FEAT1 = 0;          // 40000*512 (layer2: feat2 @0, h2 @5120000)
static constexpr size_t O_H1    = 20480000;   // A2h/A2l bf16 (20.48M float-slots); B1t alias pre-agg
static constexpr size_t O_H2    = 5120000;    // alias inside feat1 region
static constexpr size_t O_B2T   = 10240000;   // inside feat1 region, live only for layer 2
static constexpr size_t O_EW    = 40960000;   // per-layer attn scratch (1.92M floats)
static constexpr size_t O_HG    = 42880000;   // 16384
static constexpr size_t O_INT   = 42896384;   // int region start (520224 ints)
static constexpr size_t I_ROW  = 0;        // 40001
static constexpr size_t I_BSUM = 40064;    // 160
static constexpr size_t I_CNT  = 40224;    // 40000
static constexpr size_t I_FILL = 80224;    // 40000
static constexpr size_t I_EIDX = 120224;   // 400000
// pre-split x (optional, ws_size permitting):
static constexpr size_t O_A1H  = 43420000;    // 15.36M float-slots (40000*768 bf16)
static constexpr size_t O_A1L  = 58780000;    // 15.36M float-slots
static constexpr size_t WS_NEEDED = 74140000ull * 4;  // bytes

extern "C" void kernel_launch(void* const* d_in, const int* in_sizes, int n_in,
                              void* d_out, int out_size, void* d_ws, size_t ws_size,
                              hipStream_t stream)
{
    const float* x    = (const float*)d_in[0];
    const int*   src  = (const int*)d_in[1];
    const int*   dst  = (const int*)d_in[2];
    const int*   gid  = (const int*)d_in[3];
    const float* W1   = (const float*)d_in[4];
    const float* al1  = (const float*)d_in[5];
    const float* ar1  = (const float*)d_in[6];
    const float* b1   = (const float*)d_in[7];
    const float* W2   = (const float*)d_in[8];
    const float* al2  = (const float*)d_in[9];
    const float* ar2  = (const float*)d_in[10];
    const float* b2   = (const float*)d_in[11];
    const float* nW1  = (const float*)d_in[12];
    const float* nb1  = (const float*)d_in[13];
    const float* nW2  = (const float*)d_in[14];
    const float* nb2  = (const float*)d_in[15];
    const float* gW1  = (const float*)d_in[16];
    const float* gb1  = (const float*)d_in[17];
    const float* gW2  = (const float*)d_in[18];
    const float* gb2  = (const float*)d_in[19];
    float* out = (float*)d_out;
    float* ws  = (float*)d_ws;

    float* feat1 = ws + O_FEAT1;
    float* feat2 = ws + O_FEAT1;   // alias (feat1 dead after agg<4>)
    float* h2    = ws + O_H2;
    float* el1   = ws + O_EW;
    float* er1   = ws + O_EW + 160000;
    float* w1e   = ws + O_EW + 320000;
    float* el2   = ws + O_EW;
    float* er2   = ws + O_EW + 40000;
    float* w2e   = ws + O_EW + 80000;
    float* hg    = ws + O_HG;
    int*   ibase = (int*)(ws + O_INT);
    int*   row   = ibase + I_ROW;
    int*   bsum  = ibase + I_BSUM;
    int*   cnt   = ibase + I_CNT;
    int*   fill  = ibase + I_FILL;
    int*   eidx  = ibase + I_EIDX;

    // W splits. B1t shares O_H1 with A2h/A2l: B1t read by gemm L1, A2 written by agg<4> (later).
    unsigned short* B1h = (unsigned short*)(ws + O_H1);
    unsigned short* B1l = B1h + 512 * 768;
    unsigned short* B2h = (unsigned short*)(ws + O_B2T);
    unsigned short* B2l = B2h + 128 * 512;
    // layer-2 A operand (h1 as bf16 hi/lo), written directly by agg<4>:
    unsigned short* A2h = (unsigned short*)(ws + O_H1);
    unsigned short* A2l = (unsigned short*)(ws + O_H1 + 10240000);
    // optional pre-split x:
    unsigned short* A1h = (unsigned short*)(ws + O_A1H);
    unsigned short* A1l = (unsigned short*)(ws + O_A1L);
    const bool presplit = (ws_size >= WS_NEEDED);

    // ---- CSR build (depends only on dst) ----
    hipMemsetAsync(cnt, 0, NN * sizeof(int), stream);
    hist_kernel<<<(NE + 255) / 256, 256, 0, stream>>>(dst, cnt);
    scanA_kernel<<<NB_SCAN, 256, 0, stream>>>(cnt, row, bsum);
    scanB_kernel<<<1, 256, 0, stream>>>(bsum);
    scanC_kernel<<<NB_SCAN, 256, 0, stream>>>(row, bsum, fill);
    permute_kernel<<<(NE + 255) / 256, 256, 0, stream>>>(dst, fill, eidx);

    // ---- GAT layer 1 (768 -> 4x128) ----
    conv_bt<<<(512 * 768 + 255) / 256, 256, 0, stream>>>(W1, B1h, B1l, 768, 512);
    if (presplit) {
        conv_a<<<30000, 256, 0, stream>>>(x, A1h, A1l, (size_t)NN * 768 / 4);
        gemm_ps<<<1280, 256, 0, stream>>>(A1h, A1l, B1h, B1l, feat1, NN, 768, 512, 1);
    } else {
        gemm_split<<<1280, 256, 0, stream>>>(x, B1h, B1l, feat1, NN, 768, 512, 1);
    }
    eler_kernel<4><<<(NN * 4 * 64 + 255) / 256, 256, 0, stream>>>(feat1, al1, ar1, el1, er1);
    edge_w_kernel<4><<<(NE + 255) / 256, 256, 0, stream>>>(src, dst, el1, er1, w1e);
    agg_kernel<4><<<10000, 256, 0, stream>>>(row, eidx, src, w1e, feat1, b1,
                                             nullptr, A2h, A2l);

    // ---- GAT layer 2 (512 -> 1x128) ----
    conv_bt<<<(128 * 512 + 255) / 256, 256, 0, stream>>>(W2, B2h, B2l, 512, 128);
    gemm_ps<<<dim3(313, 1), 256, 0, stream>>>(A2h, A2l, B2h, B2l, feat2, NN, 512, 128, 0);
    eler_kernel<1><<<(NN * 64 + 255) / 256, 256, 0, stream>>>(feat2, al2, ar2, el2, er2);
    edge_w_kernel<1><<<(NE + 255) / 256, 256, 0, stream>>>(src, dst, el2, er2, w2e);
    agg_kernel<1><<<10000, 256, 0, stream>>>(row, eidx, src, w2e, feat2, b2,
                                             h2, nullptr, nullptr);

    // ---- pooling + MLPs ----
    graph_mean_kernel<<<NG, 128, 0, stream>>>(gid, h2, hg);
    node_mlp_kernel<<<NN, 128, 0, stream>>>(h2, nW1, nb1, nW2, nb2, out);
    graph_mlp_kernel<<<NG, 128, 0, stream>>>(hg, gW1, gb1, gW2, gb2, out + (size_t)NN * 2);
}